// Round 2
// baseline (1203.657 us; speedup 1.0000x reference)
//
#include <hip/hip_runtime.h>

#define K_CLASSES 32
#define D 128
#define EPSv 0.5f

typedef __attribute__((ext_vector_type(8))) short short8;
typedef __attribute__((ext_vector_type(4))) float f32x4;

// fp32 -> bf16 round-to-nearest-even
static __device__ inline unsigned short f2bf(float f) {
  union { float f; unsigned u; } x; x.f = f;
  unsigned r = x.u + 0x7FFFu + ((x.u >> 16) & 1u);
  return (unsigned short)(r >> 16);
}

// ---------------------------------------------------------------------------
// Per-class Gram via bf16 MFMA. One block (256 threads) per class.
// Deterministic (no atomics): list build uses per-thread chunking + wave scan.
// Also accumulates per-class column sums (for Z_mean) during staging.
// ---------------------------------------------------------------------------
__global__ __launch_bounds__(256) void class_gram_kernel(
    const float* __restrict__ Z, const int* __restrict__ Y,
    float* __restrict__ ztpiz, int* __restrict__ counts,
    float* __restrict__ percls, int m) {
  const int k = blockIdx.x;
  const int tid = threadIdx.x;
  const int lane = tid & 63;
  const int w = tid >> 6;

  __shared__ int list[3104];
  __shared__ unsigned short zs[128][40];   // [feature][sample] bf16, padded
  __shared__ int wsum[4];

  // ---- phase 1: build row list for class k (deterministic order) ----
  int run = 0;
  for (int base = 0; base < m; base += 2048) {
    const int start = base + tid * 8;
    int yv[8];
#pragma unroll
    for (int e = 0; e < 8; ++e) {
      const int r = start + e;
      yv[e] = (r < m) ? Y[r] : -1;
    }
    int cnt = 0;
#pragma unroll
    for (int e = 0; e < 8; ++e) cnt += (yv[e] == k) ? 1 : 0;
    // inclusive wave scan of cnt
    int c = cnt;
#pragma unroll
    for (int off = 1; off < 64; off <<= 1) {
      const int nbr = __shfl_up(c, off);
      if (lane >= off) c += nbr;
    }
    if (lane == 63) wsum[w] = c;
    const int excl = c - cnt;
    __syncthreads();
    int woff = 0, ctot = 0;
#pragma unroll
    for (int ww = 0; ww < 4; ++ww) {
      const int v = wsum[ww];
      if (ww < w) woff += v;
      ctot += v;
    }
    __syncthreads();  // wsum consumed before next chunk overwrites
    int pos = run + woff + excl;
#pragma unroll
    for (int e = 0; e < 8; ++e) {
      if (yv[e] == k && pos < 3072) { list[pos] = start + e; ++pos; }
    }
    run += ctot;
  }
  const int total = (run < 3072) ? run : 3072;
  const int padded = (total + 31) & ~31;
  for (int i = total + tid; i < padded; i += 256) list[i] = -1;
  __syncthreads();

  // ---- phase 2: staged bf16 MFMA accumulation ----
  const int p = tid >> 4;     // sample-pair index 0..15 (samples 2p, 2p+1)
  const int part = tid & 15;  // feature group: cols part*8 .. part*8+7
  const int l15 = lane & 15;
  const int kb = (lane >> 4) * 8;

  f32x4 acc[2][8];
#pragma unroll
  for (int r = 0; r < 2; ++r)
#pragma unroll
    for (int cb = 0; cb < 8; ++cb) acc[r][cb] = (f32x4)(0.f);

  float colacc[8];
#pragma unroll
  for (int j = 0; j < 8; ++j) colacc[j] = 0.f;

  const int nst = padded >> 5;
  for (int st = 0; st < nst; ++st) {
    const int i0 = (st << 5) + p * 2;
    const int r0 = list[i0];
    const int r1 = list[i0 + 1];
    float v0[8] = {0.f,0.f,0.f,0.f,0.f,0.f,0.f,0.f};
    float v1[8] = {0.f,0.f,0.f,0.f,0.f,0.f,0.f,0.f};
    if (r0 >= 0) {
      const float* zp = Z + (size_t)r0 * D + part * 8;
      *(float4*)&v0[0] = *(const float4*)zp;
      *(float4*)&v0[4] = *(const float4*)(zp + 4);
    }
    if (r1 >= 0) {
      const float* zp = Z + (size_t)r1 * D + part * 8;
      *(float4*)&v1[0] = *(const float4*)zp;
      *(float4*)&v1[4] = *(const float4*)(zp + 4);
    }
#pragma unroll
    for (int j = 0; j < 8; ++j) colacc[j] += v0[j] + v1[j];
    __syncthreads();  // previous stage's fragment reads complete
#pragma unroll
    for (int j = 0; j < 8; ++j) {
      const unsigned pk = (unsigned)f2bf(v0[j]) | ((unsigned)f2bf(v1[j]) << 16);
      *(unsigned*)&zs[part * 8 + j][2 * p] = pk;
    }
    __syncthreads();
    short8 frag[8];
#pragma unroll
    for (int fb = 0; fb < 8; ++fb)
      frag[fb] = *(const short8*)&zs[fb * 16 + l15][kb];
#pragma unroll
    for (int r = 0; r < 2; ++r) {
      const int rb = w * 2 + r;
#pragma unroll
      for (int cb = 0; cb < 8; ++cb)
        acc[r][cb] = __builtin_amdgcn_mfma_f32_16x16x32_bf16(
            frag[rb], frag[cb], acc[r][cb], 0, 0, 0);
    }
  }

  // ---- write per-class Gram (owner writes, no atomics) ----
  float* dst = ztpiz + (size_t)k * D * D;
  const int l4 = lane >> 4;
#pragma unroll
  for (int r = 0; r < 2; ++r) {
    const int rb = w * 2 + r;
#pragma unroll
    for (int cb = 0; cb < 8; ++cb)
#pragma unroll
      for (int q = 0; q < 4; ++q)
        dst[(rb * 16 + l4 * 4 + q) * D + cb * 16 + l15] = acc[r][cb][q];
  }

  // ---- per-class column sums (deterministic LDS reduce, reuse zs) ----
  __syncthreads();
  float* cred = (float*)&zs[0][0];  // 16*128 floats = 8 KB <= sizeof(zs)
#pragma unroll
  for (int j = 0; j < 8; ++j) cred[p * 128 + part * 8 + j] = colacc[j];
  __syncthreads();
  if (tid < 128) {
    float s = 0.f;
#pragma unroll
    for (int pp = 0; pp < 16; ++pp) s += cred[pp * 128 + tid];
    percls[k * D + tid] = s;
  }
  if (tid == 0) counts[k] = total;
}

// ---------------------------------------------------------------------------
// gram = sum_k ZtPiZ[k]  (classes partition the samples)
// ---------------------------------------------------------------------------
__global__ void sum_gram_kernel(const float* __restrict__ ztpiz,
                                float* __restrict__ gram) {
  const int e = blockIdx.x * blockDim.x + threadIdx.x;
  if (e < D * D) {
    float s = 0.f;
#pragma unroll
    for (int k = 0; k < K_CLASSES; ++k) s += ztpiz[k * D * D + e];
    gram[e] = s;
  }
}

// ---------------------------------------------------------------------------
// logdet via register-tile Cholesky of I + s*G.
// 256 threads; thread (tr,tc) owns 8x8 tile rows tr*8.., cols tc*8.. in regs.
// Per step: extract column k to LDS (2 barriers), masked rank-1 update in regs.
// ---------------------------------------------------------------------------
__global__ __launch_bounds__(256) void chol_kernel(const float* __restrict__ ztpiz,
                                                   const float* __restrict__ gram,
                                                   const int* __restrict__ counts,
                                                   float* __restrict__ ld, int m) {
  const int b = blockIdx.x;
  __shared__ float colbuf[D];
  __shared__ float red[256];
  const float* src;
  float s;
  if (b == 0) {
    src = gram;
    s = (float)D / ((float)m * EPSv);
  } else {
    src = ztpiz + (size_t)(b - 1) * D * D;
    const float cf = (float)counts[b - 1] + 1e-8f;
    s = (float)D / (cf * EPSv);
  }
  const int tr = threadIdx.x >> 4;
  const int tc = threadIdx.x & 15;
  const int R = tr * 8, C = tc * 8;

  float a[8][8];
#pragma unroll
  for (int i = 0; i < 8; ++i) {
    const float* sp = src + (size_t)(R + i) * D + C;
    float t[8];
    *(float4*)&t[0] = *(const float4*)sp;
    *(float4*)&t[4] = *(const float4*)(sp + 4);
#pragma unroll
    for (int j = 0; j < 8; ++j)
      a[i][j] = s * t[j] + ((R + i) == (C + j) ? 1.0f : 0.0f);
  }

  for (int k = 0; k < D; ++k) {
    const int ct = k >> 3, kk = k & 7;
    __syncthreads();  // prior readers of colbuf done
    if (tc == ct) {
#pragma unroll
      for (int i = 0; i < 8; ++i) colbuf[R + i] = a[i][kk];
    }
    __syncthreads();
    const float lkk = sqrtf(colbuf[k]);
    const float inv = 1.0f / lkk;
    float cr[8], cc[8];
    float tmp[8];
    *(float4*)&tmp[0] = *(const float4*)&colbuf[R];
    *(float4*)&tmp[4] = *(const float4*)&colbuf[R + 4];
#pragma unroll
    for (int i = 0; i < 8; ++i) cr[i] = (R + i > k) ? tmp[i] * inv : 0.f;
    *(float4*)&tmp[0] = *(const float4*)&colbuf[C];
    *(float4*)&tmp[4] = *(const float4*)&colbuf[C + 4];
#pragma unroll
    for (int j = 0; j < 8; ++j) cc[j] = (C + j > k) ? tmp[j] * inv : 0.f;
    if (tc == ct) {
#pragma unroll
      for (int i = 0; i < 8; ++i) {
        const int gi = R + i;
        if (gi > k) a[i][kk] = cr[i];
        else if (gi == k) a[i][kk] = lkk;
      }
    }
#pragma unroll
    for (int i = 0; i < 8; ++i)
#pragma unroll
      for (int j = 0; j < 8; ++j)
        a[i][j] = fmaf(-cr[i], cc[j], a[i][j]);
  }

  float lsum = 0.f;
  if (tr == tc) {
#pragma unroll
    for (int i = 0; i < 8; ++i) lsum += logf(a[i][i]);
  }
  red[threadIdx.x] = lsum;
  __syncthreads();
  for (int off = 128; off > 0; off >>= 1) {
    if (threadIdx.x < off) red[threadIdx.x] += red[threadIdx.x + off];
    __syncthreads();
  }
  if (threadIdx.x == 0) ld[b] = 2.0f * red[0];
}

// ---------------------------------------------------------------------------
// Assemble loss and Z_mean
// ---------------------------------------------------------------------------
__global__ void finalize_kernel(const float* __restrict__ ldv,
                                const int* __restrict__ counts,
                                const float* __restrict__ percls,
                                float* __restrict__ out, int m) {
  const int t = threadIdx.x;
  if (t < D) {
    float s = 0.f;
#pragma unroll
    for (int k = 0; k < K_CLASSES; ++k) s += percls[k * D + t];
    out[1 + K_CLASSES * D * D + t] = s / (float)m;
  }
  if (t == 0) {
    float compress = 0.f;
    for (int k = 0; k < K_CLASSES; ++k)
      compress += ldv[k + 1] * (((float)counts[k] + 1e-8f) / (float)m);
    compress *= 0.5f;
    const float discrim = 0.5f * ldv[0];
    out[0] = -discrim + compress;  // GAM2 = 1
  }
}

extern "C" void kernel_launch(void* const* d_in, const int* in_sizes, int n_in,
                              void* d_out, int out_size, void* d_ws, size_t ws_size,
                              hipStream_t stream) {
  const float* Z = (const float*)d_in[0];
  const int* Y = (const int*)d_in[1];
  float* out = (float*)d_out;
  const int m = in_sizes[0] / D;

  // workspace layout (all fully written before read; no memset needed)
  float* percls = (float*)d_ws;                          // 32*128 floats @ 0
  int* counts = (int*)((char*)d_ws + 16384);             // 32 ints
  float* ld = (float*)((char*)d_ws + 16640);             // 33 floats
  float* gram = (float*)((char*)d_ws + 20480);           // 16384 floats

  float* ztpiz = out + 1;  // (K, D, D)

  class_gram_kernel<<<K_CLASSES, 256, 0, stream>>>(Z, Y, ztpiz, counts, percls, m);
  sum_gram_kernel<<<(D * D + 255) / 256, 256, 0, stream>>>(ztpiz, gram);
  chol_kernel<<<K_CLASSES + 1, 256, 0, stream>>>(ztpiz, gram, counts, ld, m);
  finalize_kernel<<<1, 128, 0, stream>>>(ld, counts, percls, out, m);
}

// Round 3
// 195.611 us; speedup vs baseline: 6.1533x; 6.1533x over previous
//
#include <hip/hip_runtime.h>

#define K_CLASSES 32
#define D 128
#define EPSv 0.5f
#define ZPAD 42   // shorts per row: 21 dwords, coprime with 32 banks

typedef __attribute__((ext_vector_type(8))) short short8;
typedef __attribute__((ext_vector_type(4))) float f32x4;

// fp32 -> bf16 round-to-nearest-even
static __device__ inline unsigned short f2bf(float f) {
  union { float f; unsigned u; } x; x.f = f;
  unsigned r = x.u + 0x7FFFu + ((x.u >> 16) & 1u);
  return (unsigned short)(r >> 16);
}

// ---------------------------------------------------------------------------
// Per-class Gram via bf16 MFMA. One block (256 threads) per class.
// Deterministic list build (wave scan, no atomics). Column sums folded in.
// All register arrays statically indexed (rule #20).
// ---------------------------------------------------------------------------
__global__ __launch_bounds__(256) void class_gram_kernel(
    const float* __restrict__ Z, const int* __restrict__ Y,
    float* __restrict__ ztpiz, int* __restrict__ counts,
    float* __restrict__ percls, int m) {
  const int k = blockIdx.x;
  const int tid = threadIdx.x;
  const int lane = tid & 63;
  const int w = tid >> 6;

  __shared__ int list[3104];
  __shared__ unsigned short zs[128][ZPAD];  // [feature][sample] bf16
  __shared__ int wsum[4];

  // ---- phase 1: build row list for class k (deterministic order) ----
  int run = 0;
  for (int base = 0; base < m; base += 2048) {
    const int start = base + tid * 8;
    int yv[8];
#pragma unroll
    for (int e = 0; e < 8; ++e) {
      const int r = start + e;
      yv[e] = (r < m) ? Y[r] : -1;
    }
    int cnt = 0;
#pragma unroll
    for (int e = 0; e < 8; ++e) cnt += (yv[e] == k) ? 1 : 0;
    int c = cnt;
#pragma unroll
    for (int off = 1; off < 64; off <<= 1) {
      const int nbr = __shfl_up(c, off);
      if (lane >= off) c += nbr;
    }
    if (lane == 63) wsum[w] = c;
    const int excl = c - cnt;
    __syncthreads();
    int woff = 0, ctot = 0;
#pragma unroll
    for (int ww = 0; ww < 4; ++ww) {
      const int v = wsum[ww];
      if (ww < w) woff += v;
      ctot += v;
    }
    __syncthreads();
    int pos = run + woff + excl;
#pragma unroll
    for (int e = 0; e < 8; ++e) {
      if (yv[e] == k && pos < 3072) { list[pos] = start + e; ++pos; }
    }
    run += ctot;
  }
  const int total = (run < 3072) ? run : 3072;
  const int padded = (total + 31) & ~31;
  for (int i = total + tid; i < padded; i += 256) list[i] = -1;
  __syncthreads();

  // ---- phase 2: staged bf16 MFMA, global loads pipelined 1 stage ahead ----
  const int p = tid >> 4;     // sample-pair index 0..15
  const int part = tid & 15;  // feature group: part*8 .. part*8+7
  const int l15 = lane & 15;
  const int kb = (lane >> 4) * 8;
  const int rb0 = w * 2, rb1 = w * 2 + 1;

  f32x4 acc0[8], acc1[8];
#pragma unroll
  for (int cb = 0; cb < 8; ++cb) { acc0[cb] = (f32x4)(0.f); acc1[cb] = (f32x4)(0.f); }

  float colacc[8];
#pragma unroll
  for (int j = 0; j < 8; ++j) colacc[j] = 0.f;

  const int nst = padded >> 5;

  float v0[8], v1[8];
#pragma unroll
  for (int j = 0; j < 8; ++j) { v0[j] = 0.f; v1[j] = 0.f; }
  if (nst > 0) {
    const int r0 = list[p * 2];
    const int r1 = list[p * 2 + 1];
    if (r0 >= 0) {
      const float* zp = Z + (size_t)r0 * D + part * 8;
      *(float4*)&v0[0] = *(const float4*)zp;
      *(float4*)&v0[4] = *(const float4*)(zp + 4);
    }
    if (r1 >= 0) {
      const float* zp = Z + (size_t)r1 * D + part * 8;
      *(float4*)&v1[0] = *(const float4*)zp;
      *(float4*)&v1[4] = *(const float4*)(zp + 4);
    }
  }

  for (int st = 0; st < nst; ++st) {
#pragma unroll
    for (int j = 0; j < 8; ++j) colacc[j] += v0[j] + v1[j];
    __syncthreads();  // previous stage's fragment reads complete
#pragma unroll
    for (int j = 0; j < 8; ++j) {
      const unsigned pk = (unsigned)f2bf(v0[j]) | ((unsigned)f2bf(v1[j]) << 16);
      *(unsigned*)&zs[part * 8 + j][2 * p] = pk;
    }
    __syncthreads();

    // prefetch next stage (global; waits land at next iteration's use)
#pragma unroll
    for (int j = 0; j < 8; ++j) { v0[j] = 0.f; v1[j] = 0.f; }
    if (st + 1 < nst) {
      const int i0 = ((st + 1) << 5) + p * 2;
      const int r0 = list[i0];
      const int r1 = list[i0 + 1];
      if (r0 >= 0) {
        const float* zp = Z + (size_t)r0 * D + part * 8;
        *(float4*)&v0[0] = *(const float4*)zp;
        *(float4*)&v0[4] = *(const float4*)(zp + 4);
      }
      if (r1 >= 0) {
        const float* zp = Z + (size_t)r1 * D + part * 8;
        *(float4*)&v1[0] = *(const float4*)zp;
        *(float4*)&v1[4] = *(const float4*)(zp + 4);
      }
    }

    // fragments: static register indices only; runtime LDS addresses are fine
    short8 fragC[8];
#pragma unroll
    for (int fb = 0; fb < 8; ++fb)
      fragC[fb] = *(const short8*)&zs[fb * 16 + l15][kb];
    const short8 fragR0 = *(const short8*)&zs[rb0 * 16 + l15][kb];
    const short8 fragR1 = *(const short8*)&zs[rb1 * 16 + l15][kb];
#pragma unroll
    for (int cb = 0; cb < 8; ++cb) {
      acc0[cb] = __builtin_amdgcn_mfma_f32_16x16x32_bf16(fragR0, fragC[cb], acc0[cb], 0, 0, 0);
      acc1[cb] = __builtin_amdgcn_mfma_f32_16x16x32_bf16(fragR1, fragC[cb], acc1[cb], 0, 0, 0);
    }
  }

  // ---- write per-class Gram (owner writes, no atomics) ----
  float* dst = ztpiz + (size_t)k * D * D;
  const int l4 = lane >> 4;
#pragma unroll
  for (int cb = 0; cb < 8; ++cb)
#pragma unroll
    for (int q = 0; q < 4; ++q) {
      dst[(rb0 * 16 + l4 * 4 + q) * D + cb * 16 + l15] = acc0[cb][q];
      dst[(rb1 * 16 + l4 * 4 + q) * D + cb * 16 + l15] = acc1[cb][q];
    }

  // ---- per-class column sums (deterministic LDS reduce, reuse zs) ----
  __syncthreads();
  float* cred = (float*)&zs[0][0];  // 16*128 floats = 8 KB
#pragma unroll
  for (int j = 0; j < 8; ++j) cred[p * 128 + part * 8 + j] = colacc[j];
  __syncthreads();
  if (tid < 128) {
    float s = 0.f;
#pragma unroll
    for (int pp = 0; pp < 16; ++pp) s += cred[pp * 128 + tid];
    percls[k * D + tid] = s;
  }
  if (tid == 0) counts[k] = total;
}

// ---------------------------------------------------------------------------
// gram = sum_k ZtPiZ[k]
// ---------------------------------------------------------------------------
__global__ void sum_gram_kernel(const float* __restrict__ ztpiz,
                                float* __restrict__ gram) {
  const int e = blockIdx.x * blockDim.x + threadIdx.x;
  if (e < D * D) {
    float s = 0.f;
#pragma unroll
    for (int k = 0; k < K_CLASSES; ++k) s += ztpiz[k * D * D + e];
    gram[e] = s;
  }
}

// ---------------------------------------------------------------------------
// Register-tile Cholesky of I + s*G; ALL register indices compile-time.
// k-loop split: outer ct (runtime) x inner kk (unrolled 0..7).
// ---------------------------------------------------------------------------
__global__ __launch_bounds__(256) void chol_kernel(const float* __restrict__ ztpiz,
                                                   const float* __restrict__ gram,
                                                   const int* __restrict__ counts,
                                                   float* __restrict__ ld, int m) {
  const int b = blockIdx.x;
  __shared__ float colbuf[D];
  __shared__ float red[256];
  const float* src;
  float s;
  if (b == 0) {
    src = gram;
    s = (float)D / ((float)m * EPSv);
  } else {
    src = ztpiz + (size_t)(b - 1) * D * D;
    const float cf = (float)counts[b - 1] + 1e-8f;
    s = (float)D / (cf * EPSv);
  }
  const int tr = threadIdx.x >> 4;
  const int tc = threadIdx.x & 15;
  const int R = tr * 8, C = tc * 8;

  float a[8][8];
#pragma unroll
  for (int i = 0; i < 8; ++i) {
    const float* sp = src + (size_t)(R + i) * D + C;
    float t[8];
    *(float4*)&t[0] = *(const float4*)sp;
    *(float4*)&t[4] = *(const float4*)(sp + 4);
#pragma unroll
    for (int j = 0; j < 8; ++j)
      a[i][j] = s * t[j] + ((R + i) == (C + j) ? 1.0f : 0.0f);
  }

  for (int ct = 0; ct < 16; ++ct) {
#pragma unroll
    for (int kk = 0; kk < 8; ++kk) {
      const int k = ct * 8 + kk;
      __syncthreads();  // prior readers of colbuf done
      if (tc == ct) {
#pragma unroll
        for (int i = 0; i < 8; ++i) colbuf[R + i] = a[i][kk];
      }
      __syncthreads();
      const float lkk = sqrtf(colbuf[k]);
      const float inv = 1.0f / lkk;
      float cr[8], cc[8], tmp[8];
      *(float4*)&tmp[0] = *(const float4*)&colbuf[R];
      *(float4*)&tmp[4] = *(const float4*)&colbuf[R + 4];
#pragma unroll
      for (int i = 0; i < 8; ++i) cr[i] = (R + i > k) ? tmp[i] * inv : 0.f;
      *(float4*)&tmp[0] = *(const float4*)&colbuf[C];
      *(float4*)&tmp[4] = *(const float4*)&colbuf[C + 4];
#pragma unroll
      for (int j = 0; j < 8; ++j) cc[j] = (C + j > k) ? tmp[j] * inv : 0.f;
      if (tc == ct) {
#pragma unroll
        for (int i = 0; i < 8; ++i) {
          const int gi = R + i;
          a[i][kk] = (gi > k) ? cr[i] : ((gi == k) ? lkk : a[i][kk]);
        }
      }
#pragma unroll
      for (int i = 0; i < 8; ++i)
#pragma unroll
        for (int j = 0; j < 8; ++j)
          a[i][j] = fmaf(-cr[i], cc[j], a[i][j]);
    }
  }

  float lsum = 0.f;
  if (tr == tc) {
#pragma unroll
    for (int i = 0; i < 8; ++i) lsum += logf(a[i][i]);
  }
  red[threadIdx.x] = lsum;
  __syncthreads();
  for (int off = 128; off > 0; off >>= 1) {
    if (threadIdx.x < off) red[threadIdx.x] += red[threadIdx.x + off];
    __syncthreads();
  }
  if (threadIdx.x == 0) ld[b] = 2.0f * red[0];
}

// ---------------------------------------------------------------------------
// Assemble loss and Z_mean
// ---------------------------------------------------------------------------
__global__ void finalize_kernel(const float* __restrict__ ldv,
                                const int* __restrict__ counts,
                                const float* __restrict__ percls,
                                float* __restrict__ out, int m) {
  const int t = threadIdx.x;
  if (t < D) {
    float s = 0.f;
#pragma unroll
    for (int k = 0; k < K_CLASSES; ++k) s += percls[k * D + t];
    out[1 + K_CLASSES * D * D + t] = s / (float)m;
  }
  if (t == 0) {
    float compress = 0.f;
    for (int k = 0; k < K_CLASSES; ++k)
      compress += ldv[k + 1] * (((float)counts[k] + 1e-8f) / (float)m);
    compress *= 0.5f;
    const float discrim = 0.5f * ldv[0];
    out[0] = -discrim + compress;  // GAM2 = 1
  }
}

extern "C" void kernel_launch(void* const* d_in, const int* in_sizes, int n_in,
                              void* d_out, int out_size, void* d_ws, size_t ws_size,
                              hipStream_t stream) {
  const float* Z = (const float*)d_in[0];
  const int* Y = (const int*)d_in[1];
  float* out = (float*)d_out;
  const int m = in_sizes[0] / D;

  float* percls = (float*)d_ws;                // 32*128 floats @ 0
  int* counts = (int*)((char*)d_ws + 16384);   // 32 ints
  float* ld = (float*)((char*)d_ws + 16640);   // 33 floats
  float* gram = (float*)((char*)d_ws + 20480); // 16384 floats

  float* ztpiz = out + 1;  // (K, D, D)

  class_gram_kernel<<<K_CLASSES, 256, 0, stream>>>(Z, Y, ztpiz, counts, percls, m);
  sum_gram_kernel<<<(D * D + 255) / 256, 256, 0, stream>>>(ztpiz, gram);
  chol_kernel<<<K_CLASSES + 1, 256, 0, stream>>>(ztpiz, gram, counts, ld, m);
  finalize_kernel<<<1, 128, 0, stream>>>(ld, counts, percls, out, m);
}